// Round 2
// baseline (1955.802 us; speedup 1.0000x reference)
//
#include <hip/hip_runtime.h>

#define IN_F 64
#define HID_F 64
#define OUT_F 32

// ---------------------------------------------------------------------------
// Degree accumulation: 1 thread per edge, two float atomics (counts are small
// integers -> exact in fp32).
// ---------------------------------------------------------------------------
__global__ void degree_kernel(const int* __restrict__ src, const int* __restrict__ dst,
                              float* __restrict__ deg_out, float* __restrict__ deg_in,
                              int nE) {
    int e = blockIdx.x * blockDim.x + threadIdx.x;
    if (e < nE) {
        atomicAdd(&deg_out[src[e]], 1.0f);
        atomicAdd(&deg_in[dst[e]], 1.0f);
    }
}

// deg -> clamped d^{-1/2}, in place (ns/nd currently hold degrees)
__global__ void norm_kernel(float* __restrict__ ns, float* __restrict__ nd, int n) {
    int i = blockIdx.x * blockDim.x + threadIdx.x;
    if (i < n) {
        ns[i] = 1.0f / sqrtf(fmaxf(ns[i], 1.0f));
        nd[i] = 1.0f / sqrtf(fmaxf(nd[i], 1.0f));
    }
}

// ---------------------------------------------------------------------------
// Edge-parallel scatter: agg[dst] += feat[src] * ns[src]
// F/4 lanes per edge, float4 gather (16B/lane, coalesced), 4 scalar atomics
// per lane. 4 edges per 64-lane wave for F=64.
// ---------------------------------------------------------------------------
template <int F>
__global__ void scatter_kernel(const float4* __restrict__ feat4, const float* __restrict__ ns,
                               const int* __restrict__ src, const int* __restrict__ dst,
                               float* __restrict__ agg, int nE) {
    constexpr int L = F / 4;  // lanes per edge
    int t = blockIdx.x * blockDim.x + threadIdx.x;
    int e = t / L;
    int f = t % L;
    if (e < nE) {
        int s = src[e];
        int d = dst[e];
        float nsv = ns[s];
        float4 v = feat4[(size_t)s * L + f];
        float* ap = agg + (size_t)d * F + f * 4;
        atomicAdd(ap + 0, v.x * nsv);
        atomicAdd(ap + 1, v.y * nsv);
        atomicAdd(ap + 2, v.z * nsv);
        atomicAdd(ap + 3, v.w * nsv);
    }
}

// ---------------------------------------------------------------------------
// Fused: out[node][j] = relu(b[j] + nd[node] * sum_k agg[node][k] * W[k][j])
// 256 threads/block = (256/FOUT) node slots x FOUT lanes. W staged in LDS once
// per block; agg rows staged per chunk. NPB nodes per block.
// ---------------------------------------------------------------------------
template <int FIN, int FOUT, int NPB>
__global__ void gemm_bias_relu(const float* __restrict__ agg, const float* __restrict__ nd,
                               const float* __restrict__ W, const float* __restrict__ b,
                               float* __restrict__ out, int n) {
    constexpr int SLOTS = 256 / FOUT;
    constexpr int CHUNKS = NPB / SLOTS;
    __shared__ float Wl[FIN * FOUT];
    __shared__ float rows[SLOTS][FIN];

    const int tid = threadIdx.x;
    for (int i = tid; i < FIN * FOUT; i += 256) Wl[i] = W[i];

    const int slot = tid / FOUT;
    const int j = tid % FOUT;
    const float bj = b[j];
    const int base = blockIdx.x * NPB;

    for (int c = 0; c < CHUNKS; ++c) {
        const int node = base + c * SLOTS + slot;
        __syncthreads();  // Wl ready (c==0) / previous chunk's compute done
        if (node < n) {
            for (int k = j; k < FIN; k += FOUT)
                rows[slot][k] = agg[(size_t)node * FIN + k];
        }
        __syncthreads();
        if (node < n) {
            float acc = 0.0f;
#pragma unroll
            for (int k = 0; k < FIN; ++k)
                acc = fmaf(rows[slot][k], Wl[k * FOUT + j], acc);
            float v = bj + nd[node] * acc;
            out[(size_t)node * FOUT + j] = fmaxf(v, 0.0f);
        }
    }
}

extern "C" void kernel_launch(void* const* d_in, const int* in_sizes, int n_in,
                              void* d_out, int out_size, void* d_ws, size_t ws_size,
                              hipStream_t stream) {
    const float* x  = (const float*)d_in[0];
    const int* ei   = (const int*)d_in[1];
    const float* W1 = (const float*)d_in[2];
    const float* b1 = (const float*)d_in[3];
    const float* W2 = (const float*)d_in[4];
    const float* b2 = (const float*)d_in[5];
    float* out = (float*)d_out;

    const int n  = in_sizes[0] / IN_F;  // 100000 nodes
    const int nE = in_sizes[1] / 2;     // 1000000 edges
    const int* src = ei;
    const int* dst = ei + nE;

    // workspace layout: ns[n] | nd[n] | agg[n*64] | h1[n*64]  (52 MB)
    float* ws  = (float*)d_ws;
    float* ns  = ws;
    float* nd  = ws + n;
    float* agg = ws + 2 * (size_t)n;
    float* h1  = agg + (size_t)n * HID_F;

    // zero ns, nd, agg (contiguous prefix). d_ws is poisoned 0xAA each call.
    hipMemsetAsync(ws, 0, (size_t)(2 * n + n * HID_F) * sizeof(float), stream);

    degree_kernel<<<(nE + 255) / 256, 256, 0, stream>>>(src, dst, ns, nd, nE);
    norm_kernel<<<(n + 255) / 256, 256, 0, stream>>>(ns, nd, n);

    // ---- layer 1: agg = scatter(x * ns); h1 = relu(nd * (agg @ W1) + b1)
    {
        const int threads = 256;
        long long tot = (long long)nE * (IN_F / 4);
        int blocks = (int)((tot + threads - 1) / threads);
        scatter_kernel<IN_F><<<blocks, threads, 0, stream>>>(
            (const float4*)x, ns, src, dst, agg, nE);
    }
    gemm_bias_relu<IN_F, HID_F, 32><<<(n + 31) / 32, 256, 0, stream>>>(agg, nd, W1, b1, h1, n);

    // re-zero agg for layer 2 (stream-ordered after gemm read it)
    hipMemsetAsync(agg, 0, (size_t)n * HID_F * sizeof(float), stream);

    // ---- layer 2: agg = scatter(h1 * ns); out = relu(nd * (agg @ W2) + b2)
    {
        const int threads = 256;
        long long tot = (long long)nE * (HID_F / 4);
        int blocks = (int)((tot + threads - 1) / threads);
        scatter_kernel<HID_F><<<blocks, threads, 0, stream>>>(
            (const float4*)h1, ns, src, dst, agg, nE);
    }
    gemm_bias_relu<HID_F, OUT_F, 32><<<(n + 31) / 32, 256, 0, stream>>>(agg, nd, W2, b2, out, n);
}

// Round 3
// 376.896 us; speedup vs baseline: 5.1892x; 5.1892x over previous
//
#include <hip/hip_runtime.h>

#define IN_F 64
#define HID_F 64
#define OUT_F 32
#define SCAN_B 256

// ---------------------------------------------------------------------------
// Int degree histogram: deg_out[src]++, deg_in[dst]++. 400KB counter arrays
// stay L2-resident; 2M int atomics total.
// ---------------------------------------------------------------------------
__global__ void degree_kernel(const int* __restrict__ src, const int* __restrict__ dst,
                              int* __restrict__ dout, int* __restrict__ din, int nE) {
    int e = blockIdx.x * blockDim.x + threadIdx.x;
    if (e < nE) {
        atomicAdd(&dout[src[e]], 1);
        atomicAdd(&din[dst[e]], 1);
    }
}

// deg(int) -> clamped d^{-1/2} (float)
__global__ void norm_kernel(const int* __restrict__ dout, const int* __restrict__ din,
                            float* __restrict__ ns, float* __restrict__ nd, int n) {
    int i = blockIdx.x * blockDim.x + threadIdx.x;
    if (i < n) {
        ns[i] = 1.0f / sqrtf(fmaxf((float)dout[i], 1.0f));
        nd[i] = 1.0f / sqrtf(fmaxf((float)din[i], 1.0f));
    }
}

// ---------------------------------------------------------------------------
// Exclusive scan of din -> row_ptr (3-kernel hierarchical scan).
// ---------------------------------------------------------------------------
__global__ void scan_block(const int* __restrict__ counts, int* __restrict__ row_ptr,
                           int* __restrict__ bsums, int n) {
    __shared__ int tmp[SCAN_B];
    int t = threadIdx.x;
    int i = blockIdx.x * SCAN_B + t;
    int v = (i < n) ? counts[i] : 0;
    tmp[t] = v;
    __syncthreads();
    for (int off = 1; off < SCAN_B; off <<= 1) {
        int a = (t >= off) ? tmp[t - off] : 0;
        __syncthreads();
        tmp[t] += a;
        __syncthreads();
    }
    if (i < n) row_ptr[i] = tmp[t] - v;          // exclusive within block
    if (t == SCAN_B - 1) bsums[blockIdx.x] = tmp[t];
}

__global__ void scan_sums(int* __restrict__ bsums, int nb) {  // nb <= 512, 1 block
    __shared__ int tmp[512];
    int t = threadIdx.x;
    int v = (t < nb) ? bsums[t] : 0;
    tmp[t] = v;
    __syncthreads();
    for (int off = 1; off < 512; off <<= 1) {
        int a = (t >= off) ? tmp[t - off] : 0;
        __syncthreads();
        tmp[t] += a;
        __syncthreads();
    }
    if (t < nb) bsums[t] = tmp[t] - v;           // exclusive block offsets
}

__global__ void scan_add(int* __restrict__ row_ptr, const int* __restrict__ bsums,
                         int n, int nE) {
    int i = blockIdx.x * SCAN_B + threadIdx.x;
    if (i < n) row_ptr[i] += bsums[blockIdx.x];
    if (i == 0) row_ptr[n] = nE;
}

// ---------------------------------------------------------------------------
// CSR bucket fill: csr_src[row_ptr[dst[e]] + pos] = src[e]
// ---------------------------------------------------------------------------
__global__ void fill_csr(const int* __restrict__ src, const int* __restrict__ dst,
                         const int* __restrict__ row_ptr, int* __restrict__ cursor,
                         int* __restrict__ csr_src, int nE) {
    int e = blockIdx.x * blockDim.x + threadIdx.x;
    if (e < nE) {
        int d = dst[e];
        int pos = atomicAdd(&cursor[d], 1);
        csr_src[row_ptr[d] + pos] = src[e];
    }
}

// ---------------------------------------------------------------------------
// Fused per-layer kernel: for each node,
//   row = nd[node] * sum_{s in in(node)} feat[s] * (SRC_SCALE ? ns[s] : 1)
//   out[node][j] = relu(b[j] + sum_k row[k]*W[k][j]) * (OUT_SCALE ? ns[node] : 1)
// 256 threads = 16 node-slots x 16 lanes; float4 register accumulation;
// W staged in LDS; row pushed through padded LDS for the dense transform.
// ---------------------------------------------------------------------------
template <int FIN, int FOUT, bool SRC_SCALE, bool OUT_SCALE>
__global__ void agg_gemm_kernel(const float4* __restrict__ feat4,
                                const float* __restrict__ ns, const float* __restrict__ nd,
                                const int* __restrict__ row_ptr, const int* __restrict__ csr_src,
                                const float* __restrict__ W, const float* __restrict__ b,
                                float* __restrict__ out, int n) {
    constexpr int SLOTS = 16;
    constexpr int JPL = FOUT / 16;          // outputs per lane (4 or 2)
    __shared__ float Wl[FIN * FOUT];
    __shared__ float rows[SLOTS][FIN + 4];  // +4 pad: 16B-aligned rows, conflict-free

    const int tid = threadIdx.x;
    for (int i = tid; i < FIN * FOUT; i += 256) Wl[i] = W[i];

    const int slot = tid >> 4;
    const int lane = tid & 15;

    float bj[JPL];
#pragma unroll
    for (int q = 0; q < JPL; ++q) bj[q] = b[lane * JPL + q];

    const int ngroups = (n + SLOTS - 1) / SLOTS;
    for (int g = blockIdx.x; g < ngroups; g += gridDim.x) {
        const int node = g * SLOTS + slot;
        float4 acc = make_float4(0.f, 0.f, 0.f, 0.f);
        if (node < n) {
            const int beg = row_ptr[node], end = row_ptr[node + 1];
            for (int i = beg; i < end; ++i) {
                const int s = csr_src[i];
                const float4 v = feat4[(size_t)s * (FIN / 4) + lane];
                const float w = SRC_SCALE ? ns[s] : 1.0f;
                acc.x = fmaf(v.x, w, acc.x);
                acc.y = fmaf(v.y, w, acc.y);
                acc.z = fmaf(v.z, w, acc.z);
                acc.w = fmaf(v.w, w, acc.w);
            }
            const float ndv = nd[node];
            acc.x *= ndv; acc.y *= ndv; acc.z *= ndv; acc.w *= ndv;
        }
        __syncthreads();  // rows free (and Wl ready on first pass)
        rows[slot][lane * 4 + 0] = acc.x;
        rows[slot][lane * 4 + 1] = acc.y;
        rows[slot][lane * 4 + 2] = acc.z;
        rows[slot][lane * 4 + 3] = acc.w;
        __syncthreads();
        if (node < n) {
            float o[JPL];
#pragma unroll
            for (int q = 0; q < JPL; ++q) o[q] = bj[q];
            for (int k = 0; k < FIN; ++k) {
                const float r = rows[slot][k];
#pragma unroll
                for (int q = 0; q < JPL; ++q)
                    o[q] = fmaf(r, Wl[k * FOUT + lane * JPL + q], o[q]);
            }
            const float os = OUT_SCALE ? ns[node] : 1.0f;
#pragma unroll
            for (int q = 0; q < JPL; ++q)
                out[(size_t)node * FOUT + lane * JPL + q] = fmaxf(o[q], 0.0f) * os;
        }
    }
}

extern "C" void kernel_launch(void* const* d_in, const int* in_sizes, int n_in,
                              void* d_out, int out_size, void* d_ws, size_t ws_size,
                              hipStream_t stream) {
    const float* x  = (const float*)d_in[0];
    const int* ei   = (const int*)d_in[1];
    const float* W1 = (const float*)d_in[2];
    const float* b1 = (const float*)d_in[3];
    const float* W2 = (const float*)d_in[4];
    const float* b2 = (const float*)d_in[5];
    float* out = (float*)d_out;

    const int n  = in_sizes[0] / IN_F;  // 100000
    const int nE = in_sizes[1] / 2;     // 1000000
    const int* src = ei;
    const int* dst = ei + nE;

    // workspace layout (all 16B-aligned by construction; n and nE are /4)
    int* din     = (int*)d_ws;           // n   (zeroed)
    int* dout    = din + n;              // n   (zeroed)
    int* cursor  = dout + n;             // n   (zeroed)
    int* row_ptr = cursor + n;           // n+4
    int* bsums   = row_ptr + n + 4;      // 512
    int* csr_src = bsums + 512;          // nE
    float* ns    = (float*)(csr_src + nE);  // n
    float* nd    = ns + n;                  // n
    float* h1s   = nd + n;                  // n*HID_F (written fully, no init)

    hipMemsetAsync(d_ws, 0, (size_t)3 * n * sizeof(int), stream);

    const int eb = (nE + 255) / 256;
    const int nb = (n + SCAN_B - 1) / SCAN_B;  // 391 <= 512

    degree_kernel<<<eb, 256, 0, stream>>>(src, dst, dout, din, nE);
    norm_kernel<<<(n + 255) / 256, 256, 0, stream>>>(dout, din, ns, nd, n);
    scan_block<<<nb, SCAN_B, 0, stream>>>(din, row_ptr, bsums, n);
    scan_sums<<<1, 512, 0, stream>>>(bsums, nb);
    scan_add<<<nb, SCAN_B, 0, stream>>>(row_ptr, bsums, n, nE);
    fill_csr<<<eb, 256, 0, stream>>>(src, dst, row_ptr, cursor, csr_src, nE);

    // layer 1: gather x*ns -> *nd -> @W1+b1 -> relu -> *ns (pre-scale for L2)
    agg_gemm_kernel<IN_F, HID_F, true, true><<<2048, 256, 0, stream>>>(
        (const float4*)x, ns, nd, row_ptr, csr_src, W1, b1, h1s, n);
    // layer 2: gather h1s (already ns-scaled) -> *nd -> @W2+b2 -> relu
    agg_gemm_kernel<HID_F, OUT_F, false, false><<<2048, 256, 0, stream>>>(
        (const float4*)h1s, ns, nd, row_ptr, csr_src, W2, b2, out, n);
}

// Round 6
// 333.552 us; speedup vs baseline: 5.8636x; 1.1299x over previous
//
#include <hip/hip_runtime.h>

#define IN_F 64
#define HID_F 64
#define OUT_F 32
#define SCAN_B 256

// Compile-time fence: prevents hipcc from reordering LDS ops across the
// wave-lockstep handoff points (no runtime cost, no s_barrier emitted).
#define WAVE_BAR() __builtin_amdgcn_wave_barrier()

// ---------------------------------------------------------------------------
// Int degree histogram, 4 edges/thread (int4 loads, 8 independent atomics).
// Counter arrays are L2-resident; 2M int atomics total.
// ---------------------------------------------------------------------------
__global__ void degree_kernel(const int* __restrict__ src, const int* __restrict__ dst,
                              int* __restrict__ dout, int* __restrict__ din, int nE) {
    int e4 = blockIdx.x * blockDim.x + threadIdx.x;
    int base = e4 * 4;
    if (base + 3 < nE) {
        int4 s = *(const int4*)(src + base);
        int4 d = *(const int4*)(dst + base);
        atomicAdd(&dout[s.x], 1); atomicAdd(&dout[s.y], 1);
        atomicAdd(&dout[s.z], 1); atomicAdd(&dout[s.w], 1);
        atomicAdd(&din[d.x], 1); atomicAdd(&din[d.y], 1);
        atomicAdd(&din[d.z], 1); atomicAdd(&din[d.w], 1);
    } else {
        for (int e = base; e < nE; ++e) {
            atomicAdd(&dout[src[e]], 1);
            atomicAdd(&din[dst[e]], 1);
        }
    }
}

// ---------------------------------------------------------------------------
// Block scan of din -> row_ptr (exclusive, per-block) + fused norm compute
// ---------------------------------------------------------------------------
__global__ void scan_norm_block(const int* __restrict__ din, const int* __restrict__ dout,
                                float* __restrict__ ns, float* __restrict__ nd,
                                int* __restrict__ row_ptr, int* __restrict__ bsums, int n) {
    __shared__ int tmp[SCAN_B];
    int t = threadIdx.x;
    int i = blockIdx.x * SCAN_B + t;
    int v = (i < n) ? din[i] : 0;
    if (i < n) {
        nd[i] = 1.0f / sqrtf(fmaxf((float)v, 1.0f));
        ns[i] = 1.0f / sqrtf(fmaxf((float)dout[i], 1.0f));
    }
    tmp[t] = v;
    __syncthreads();
    for (int off = 1; off < SCAN_B; off <<= 1) {
        int a = (t >= off) ? tmp[t - off] : 0;
        __syncthreads();
        tmp[t] += a;
        __syncthreads();
    }
    if (i < n) row_ptr[i] = tmp[t] - v;
    if (t == SCAN_B - 1) bsums[blockIdx.x] = tmp[t];
}

__global__ void scan_sums(int* __restrict__ bsums, int nb) {  // nb <= 512, 1 block
    __shared__ int tmp[512];
    int t = threadIdx.x;
    int v = (t < nb) ? bsums[t] : 0;
    tmp[t] = v;
    __syncthreads();
    for (int off = 1; off < 512; off <<= 1) {
        int a = (t >= off) ? tmp[t - off] : 0;
        __syncthreads();
        tmp[t] += a;
        __syncthreads();
    }
    if (t < nb) bsums[t] = tmp[t] - v;
}

__global__ void scan_add(int* __restrict__ row_ptr, const int* __restrict__ bsums,
                         int n, int nE) {
    int i = blockIdx.x * SCAN_B + threadIdx.x;
    if (i < n) row_ptr[i] += bsums[blockIdx.x];
    if (i == 0) row_ptr[n] = nE;
}

// ---------------------------------------------------------------------------
// CSR bucket fill, 4 edges/thread (int4 loads, independent atomic chains).
// ---------------------------------------------------------------------------
__global__ void fill_csr(const int* __restrict__ src, const int* __restrict__ dst,
                         const int* __restrict__ row_ptr, int* __restrict__ cursor,
                         int* __restrict__ csr_src, int nE) {
    int e4 = blockIdx.x * blockDim.x + threadIdx.x;
    int base = e4 * 4;
    if (base + 3 < nE) {
        int4 s = *(const int4*)(src + base);
        int4 d = *(const int4*)(dst + base);
        int p0 = atomicAdd(&cursor[d.x], 1);
        int p1 = atomicAdd(&cursor[d.y], 1);
        int p2 = atomicAdd(&cursor[d.z], 1);
        int p3 = atomicAdd(&cursor[d.w], 1);
        csr_src[row_ptr[d.x] + p0] = s.x;
        csr_src[row_ptr[d.y] + p1] = s.y;
        csr_src[row_ptr[d.z] + p2] = s.z;
        csr_src[row_ptr[d.w] + p3] = s.w;
    } else {
        for (int e = base; e < nE; ++e) {
            int d = dst[e];
            int pos = atomicAdd(&cursor[d], 1);
            csr_src[row_ptr[d] + pos] = src[e];
        }
    }
}

// ---------------------------------------------------------------------------
// Layer 1 fused: per node,
//   agg  = nd[v] * sum_{s in in(v)} x[s]*ns[s]          (4-way unrolled gather)
//   h1s  = relu(agg @ W1 + b1) * ns[v]
//   t2   = h1s @ W2                                      -> written (32-wide)
// 256 thr = 16 slots x 16 lanes; a slot's lanes live in ONE wave, so the
// rows[] handoffs need only compiler fences (WAVE_BAR), not __syncthreads.
// ---------------------------------------------------------------------------
__global__ __launch_bounds__(256) void layer1_kernel(
    const float4* __restrict__ x4, const float* __restrict__ ns, const float* __restrict__ nd,
    const int* __restrict__ row_ptr, const int* __restrict__ csr_src,
    const float* __restrict__ W1, const float* __restrict__ b1,
    const float* __restrict__ W2, float* __restrict__ t2, int n) {
    __shared__ float W1l[64 * 64];
    __shared__ float W2l[64 * 32];
    __shared__ float rows[16][68];

    const int tid = threadIdx.x;
    for (int i = tid; i < 64 * 64; i += 256) W1l[i] = W1[i];
    for (int i = tid; i < 64 * 32; i += 256) W2l[i] = W2[i];
    __syncthreads();

    const int slot = tid >> 4;
    const int lane = tid & 15;
    float bj0 = b1[lane * 4 + 0], bj1 = b1[lane * 4 + 1];
    float bj2 = b1[lane * 4 + 2], bj3 = b1[lane * 4 + 3];

    const int ngroups = (n + 15) >> 4;
    for (int g = blockIdx.x; g < ngroups; g += gridDim.x) {
        const int node = g * 16 + slot;
        if (node >= n) continue;

        float4 a0 = {0, 0, 0, 0}, a1 = {0, 0, 0, 0}, a2 = {0, 0, 0, 0}, a3 = {0, 0, 0, 0};
        const int beg = row_ptr[node], end = row_ptr[node + 1];
        int i = beg;
        for (; i + 4 <= end; i += 4) {
            int s0 = csr_src[i], s1 = csr_src[i + 1], s2 = csr_src[i + 2], s3 = csr_src[i + 3];
            float4 v0 = x4[(size_t)s0 * 16 + lane];
            float4 v1 = x4[(size_t)s1 * 16 + lane];
            float4 v2 = x4[(size_t)s2 * 16 + lane];
            float4 v3 = x4[(size_t)s3 * 16 + lane];
            float w0 = ns[s0], w1 = ns[s1], w2 = ns[s2], w3 = ns[s3];
            a0.x = fmaf(v0.x, w0, a0.x); a0.y = fmaf(v0.y, w0, a0.y);
            a0.z = fmaf(v0.z, w0, a0.z); a0.w = fmaf(v0.w, w0, a0.w);
            a1.x = fmaf(v1.x, w1, a1.x); a1.y = fmaf(v1.y, w1, a1.y);
            a1.z = fmaf(v1.z, w1, a1.z); a1.w = fmaf(v1.w, w1, a1.w);
            a2.x = fmaf(v2.x, w2, a2.x); a2.y = fmaf(v2.y, w2, a2.y);
            a2.z = fmaf(v2.z, w2, a2.z); a2.w = fmaf(v2.w, w2, a2.w);
            a3.x = fmaf(v3.x, w3, a3.x); a3.y = fmaf(v3.y, w3, a3.y);
            a3.z = fmaf(v3.z, w3, a3.z); a3.w = fmaf(v3.w, w3, a3.w);
        }
        for (; i < end; ++i) {
            int s = csr_src[i];
            float4 v = x4[(size_t)s * 16 + lane];
            float w = ns[s];
            a0.x = fmaf(v.x, w, a0.x); a0.y = fmaf(v.y, w, a0.y);
            a0.z = fmaf(v.z, w, a0.z); a0.w = fmaf(v.w, w, a0.w);
        }
        const float ndv = nd[node];
        float rx = (a0.x + a1.x + a2.x + a3.x) * ndv;
        float ry = (a0.y + a1.y + a2.y + a3.y) * ndv;
        float rz = (a0.z + a1.z + a2.z + a3.z) * ndv;
        float rw = (a0.w + a1.w + a2.w + a3.w) * ndv;

        WAVE_BAR();  // prior iteration's GEMM2 reads done before overwrite
        rows[slot][lane * 4 + 0] = rx;
        rows[slot][lane * 4 + 1] = ry;
        rows[slot][lane * 4 + 2] = rz;
        rows[slot][lane * 4 + 3] = rw;
        WAVE_BAR();  // agg row visible to all 16 lanes of this slot

        float o0 = bj0, o1 = bj1, o2 = bj2, o3 = bj3;
#pragma unroll
        for (int k = 0; k < 64; ++k) {
            const float r = rows[slot][k];
            o0 = fmaf(r, W1l[k * 64 + lane * 4 + 0], o0);
            o1 = fmaf(r, W1l[k * 64 + lane * 4 + 1], o1);
            o2 = fmaf(r, W1l[k * 64 + lane * 4 + 2], o2);
            o3 = fmaf(r, W1l[k * 64 + lane * 4 + 3], o3);
        }
        const float nsv = ns[node];
        o0 = fmaxf(o0, 0.0f) * nsv; o1 = fmaxf(o1, 0.0f) * nsv;
        o2 = fmaxf(o2, 0.0f) * nsv; o3 = fmaxf(o3, 0.0f) * nsv;

        WAVE_BAR();  // GEMM1 reads done before h1s overwrite
        rows[slot][lane * 4 + 0] = o0;
        rows[slot][lane * 4 + 1] = o1;
        rows[slot][lane * 4 + 2] = o2;
        rows[slot][lane * 4 + 3] = o3;
        WAVE_BAR();  // h1s row visible

        float p0 = 0.0f, p1 = 0.0f;
#pragma unroll
        for (int k = 0; k < 64; ++k) {
            const float r = rows[slot][k];
            p0 = fmaf(r, W2l[k * 32 + lane * 2 + 0], p0);
            p1 = fmaf(r, W2l[k * 32 + lane * 2 + 1], p1);
        }
        t2[(size_t)node * 32 + lane * 2 + 0] = p0;
        t2[(size_t)node * 32 + lane * 2 + 1] = p1;
    }
}

// ---------------------------------------------------------------------------
// Layer 2: out[v] = relu(nd[v] * sum_{s in in(v)} t2[s] + b2)
// 8 lanes x float4 per node, 32 nodes per 256-thr block, 4-way unroll.
// ---------------------------------------------------------------------------
__global__ __launch_bounds__(256) void layer2_kernel(
    const float4* __restrict__ t24, const float* __restrict__ nd,
    const int* __restrict__ row_ptr, const int* __restrict__ csr_src,
    const float* __restrict__ b2, float4* __restrict__ out4, int n) {
    const int t = blockIdx.x * blockDim.x + threadIdx.x;
    const int node = t >> 3;
    const int lane = t & 7;
    if (node >= n) return;

    float4 a0 = {0, 0, 0, 0}, a1 = {0, 0, 0, 0}, a2 = {0, 0, 0, 0}, a3 = {0, 0, 0, 0};
    const int beg = row_ptr[node], end = row_ptr[node + 1];
    int i = beg;
    for (; i + 4 <= end; i += 4) {
        int s0 = csr_src[i], s1 = csr_src[i + 1], s2 = csr_src[i + 2], s3 = csr_src[i + 3];
        float4 v0 = t24[(size_t)s0 * 8 + lane];
        float4 v1 = t24[(size_t)s1 * 8 + lane];
        float4 v2 = t24[(size_t)s2 * 8 + lane];
        float4 v3 = t24[(size_t)s3 * 8 + lane];
        a0.x += v0.x; a0.y += v0.y; a0.z += v0.z; a0.w += v0.w;
        a1.x += v1.x; a1.y += v1.y; a1.z += v1.z; a1.w += v1.w;
        a2.x += v2.x; a2.y += v2.y; a2.z += v2.z; a2.w += v2.w;
        a3.x += v3.x; a3.y += v3.y; a3.z += v3.z; a3.w += v3.w;
    }
    for (; i < end; ++i) {
        float4 v = t24[(size_t)csr_src[i] * 8 + lane];
        a0.x += v.x; a0.y += v.y; a0.z += v.z; a0.w += v.w;
    }
    const float ndv = nd[node];
    const float4 bb = ((const float4*)b2)[lane];
    float4 r;
    r.x = fmaxf(fmaf(a0.x + a1.x + a2.x + a3.x, ndv, bb.x), 0.0f);
    r.y = fmaxf(fmaf(a0.y + a1.y + a2.y + a3.y, ndv, bb.y), 0.0f);
    r.z = fmaxf(fmaf(a0.z + a1.z + a2.z + a3.z, ndv, bb.z), 0.0f);
    r.w = fmaxf(fmaf(a0.w + a1.w + a2.w + a3.w, ndv, bb.w), 0.0f);
    out4[(size_t)node * 8 + lane] = r;
}

extern "C" void kernel_launch(void* const* d_in, const int* in_sizes, int n_in,
                              void* d_out, int out_size, void* d_ws, size_t ws_size,
                              hipStream_t stream) {
    const float* x  = (const float*)d_in[0];
    const int* ei   = (const int*)d_in[1];
    const float* W1 = (const float*)d_in[2];
    const float* b1 = (const float*)d_in[3];
    const float* W2 = (const float*)d_in[4];
    const float* b2 = (const float*)d_in[5];
    float* out = (float*)d_out;

    const int n  = in_sizes[0] / IN_F;  // 100000
    const int nE = in_sizes[1] / 2;     // 1000000
    const int* src = ei;
    const int* dst = ei + nE;

    // workspace: din[n] dout[n] cursor[n] row_ptr[n+4] bsums[512] csr_src[nE]
    //            ns[n] nd[n] t2[n*32]   (~20 MB, all 16B-aligned)
    int* din     = (int*)d_ws;
    int* dout    = din + n;
    int* cursor  = dout + n;
    int* row_ptr = cursor + n;
    int* bsums   = row_ptr + n + 4;
    int* csr_src = bsums + 512;
    float* ns    = (float*)(csr_src + nE);
    float* nd    = ns + n;
    float* t2    = nd + n;

    hipMemsetAsync(d_ws, 0, (size_t)3 * n * sizeof(int), stream);

    const int e4b = (nE / 4 + 255) / 256 + 1;  // 4 edges/thread (tail-guarded)
    const int nb = (n + SCAN_B - 1) / SCAN_B;  // 391 <= 512

    degree_kernel<<<e4b, 256, 0, stream>>>(src, dst, dout, din, nE);
    scan_norm_block<<<nb, SCAN_B, 0, stream>>>(din, dout, ns, nd, row_ptr, bsums, n);
    scan_sums<<<1, 512, 0, stream>>>(bsums, nb);
    scan_add<<<nb, SCAN_B, 0, stream>>>(row_ptr, bsums, n, nE);
    fill_csr<<<e4b, 256, 0, stream>>>(src, dst, row_ptr, cursor, csr_src, nE);

    layer1_kernel<<<2048, 256, 0, stream>>>(
        (const float4*)x, ns, nd, row_ptr, csr_src, W1, b1, W2, t2, n);
    layer2_kernel<<<(n * 8 + 255) / 256, 256, 0, stream>>>(
        (const float4*)t2, nd, row_ptr, csr_src, b2, (float4*)out, n);
}

// Round 7
// 286.506 us; speedup vs baseline: 6.8264x; 1.1642x over previous
//
#include <hip/hip_runtime.h>

#define IN_F 64
#define HID_F 64
#define OUT_F 32
#define SCAN_B 256

// Compile-time fence: prevents hipcc from reordering LDS ops across the
// wave-lockstep handoff points (no runtime cost, no s_barrier emitted).
#define WAVE_BAR() __builtin_amdgcn_wave_barrier()

// ---------------------------------------------------------------------------
// Degree histogram + per-edge rank, 8 edges/thread.
// The din atomic's return value is the edge's rank within its dst bucket:
// rank[e] = old din[dst[e]]  -- captured for free, stored coalesced.
// ---------------------------------------------------------------------------
__global__ void degree_rank_kernel(const int* __restrict__ src, const int* __restrict__ dst,
                                   int* __restrict__ dout, int* __restrict__ din,
                                   int* __restrict__ rank, int nE) {
    int t = blockIdx.x * blockDim.x + threadIdx.x;
    int base = t * 8;
    if (base + 7 < nE) {
        int4 sa = *(const int4*)(src + base);
        int4 sb = *(const int4*)(src + base + 4);
        int4 da = *(const int4*)(dst + base);
        int4 db = *(const int4*)(dst + base + 4);
        atomicAdd(&dout[sa.x], 1); atomicAdd(&dout[sa.y], 1);
        atomicAdd(&dout[sa.z], 1); atomicAdd(&dout[sa.w], 1);
        atomicAdd(&dout[sb.x], 1); atomicAdd(&dout[sb.y], 1);
        atomicAdd(&dout[sb.z], 1); atomicAdd(&dout[sb.w], 1);
        int4 ra, rb;
        ra.x = atomicAdd(&din[da.x], 1); ra.y = atomicAdd(&din[da.y], 1);
        ra.z = atomicAdd(&din[da.z], 1); ra.w = atomicAdd(&din[da.w], 1);
        rb.x = atomicAdd(&din[db.x], 1); rb.y = atomicAdd(&din[db.y], 1);
        rb.z = atomicAdd(&din[db.z], 1); rb.w = atomicAdd(&din[db.w], 1);
        *(int4*)(rank + base) = ra;
        *(int4*)(rank + base + 4) = rb;
    } else {
        for (int e = base; e < nE; ++e) {
            atomicAdd(&dout[src[e]], 1);
            rank[e] = atomicAdd(&din[dst[e]], 1);
        }
    }
}

// ---------------------------------------------------------------------------
// Block scan of din -> row_ptr (exclusive, per-block) + fused norm compute
// ---------------------------------------------------------------------------
__global__ void scan_norm_block(const int* __restrict__ din, const int* __restrict__ dout,
                                float* __restrict__ ns, float* __restrict__ nd,
                                int* __restrict__ row_ptr, int* __restrict__ bsums, int n) {
    __shared__ int tmp[SCAN_B];
    int t = threadIdx.x;
    int i = blockIdx.x * SCAN_B + t;
    int v = (i < n) ? din[i] : 0;
    if (i < n) {
        nd[i] = 1.0f / sqrtf(fmaxf((float)v, 1.0f));
        ns[i] = 1.0f / sqrtf(fmaxf((float)dout[i], 1.0f));
    }
    tmp[t] = v;
    __syncthreads();
    for (int off = 1; off < SCAN_B; off <<= 1) {
        int a = (t >= off) ? tmp[t - off] : 0;
        __syncthreads();
        tmp[t] += a;
        __syncthreads();
    }
    if (i < n) row_ptr[i] = tmp[t] - v;
    if (t == SCAN_B - 1) bsums[blockIdx.x] = tmp[t];
}

__global__ void scan_sums(int* __restrict__ bsums, int nb) {  // nb <= 512, 1 block
    __shared__ int tmp[512];
    int t = threadIdx.x;
    int v = (t < nb) ? bsums[t] : 0;
    tmp[t] = v;
    __syncthreads();
    for (int off = 1; off < 512; off <<= 1) {
        int a = (t >= off) ? tmp[t - off] : 0;
        __syncthreads();
        tmp[t] += a;
        __syncthreads();
    }
    if (t < nb) bsums[t] = tmp[t] - v;
}

__global__ void scan_add(int* __restrict__ row_ptr, const int* __restrict__ bsums,
                         int n, int nE) {
    int i = blockIdx.x * SCAN_B + threadIdx.x;
    if (i < n) row_ptr[i] += bsums[blockIdx.x];
    if (i == 0) row_ptr[n] = nE;
}

// ---------------------------------------------------------------------------
// Atomic-free CSR fill, 8 edges/thread:
//   csr_src[row_ptr[dst[e]] + rank[e]] = src[e]
// Sequential loads; one L2-resident row_ptr read + one scattered 4B write per
// edge. No cursor, no atomic round-trip.
// ---------------------------------------------------------------------------
__global__ void fill_csr(const int* __restrict__ src, const int* __restrict__ dst,
                         const int* __restrict__ rank, const int* __restrict__ row_ptr,
                         int* __restrict__ csr_src, int nE) {
    int t = blockIdx.x * blockDim.x + threadIdx.x;
    int base = t * 8;
    if (base + 7 < nE) {
        int4 sa = *(const int4*)(src + base);
        int4 sb = *(const int4*)(src + base + 4);
        int4 da = *(const int4*)(dst + base);
        int4 db = *(const int4*)(dst + base + 4);
        int4 ra = *(const int4*)(rank + base);
        int4 rb = *(const int4*)(rank + base + 4);
        csr_src[row_ptr[da.x] + ra.x] = sa.x;
        csr_src[row_ptr[da.y] + ra.y] = sa.y;
        csr_src[row_ptr[da.z] + ra.z] = sa.z;
        csr_src[row_ptr[da.w] + ra.w] = sa.w;
        csr_src[row_ptr[db.x] + rb.x] = sb.x;
        csr_src[row_ptr[db.y] + rb.y] = sb.y;
        csr_src[row_ptr[db.z] + rb.z] = sb.z;
        csr_src[row_ptr[db.w] + rb.w] = sb.w;
    } else {
        for (int e = base; e < nE; ++e)
            csr_src[row_ptr[dst[e]] + rank[e]] = src[e];
    }
}

// ---------------------------------------------------------------------------
// Layer 1 fused: per node,
//   agg  = nd[v] * sum_{s in in(v)} x[s]*ns[s]          (4-way unrolled gather)
//   h1s  = relu(agg @ W1 + b1) * ns[v]
//   t2   = h1s @ W2                                      -> written (32-wide)
// 256 thr = 16 slots x 16 lanes; a slot's lanes live in ONE wave, so the
// rows[] handoffs need only compiler fences (WAVE_BAR), not __syncthreads.
// ---------------------------------------------------------------------------
__global__ __launch_bounds__(256) void layer1_kernel(
    const float4* __restrict__ x4, const float* __restrict__ ns, const float* __restrict__ nd,
    const int* __restrict__ row_ptr, const int* __restrict__ csr_src,
    const float* __restrict__ W1, const float* __restrict__ b1,
    const float* __restrict__ W2, float* __restrict__ t2, int n) {
    __shared__ float W1l[64 * 64];
    __shared__ float W2l[64 * 32];
    __shared__ float rows[16][68];

    const int tid = threadIdx.x;
    for (int i = tid; i < 64 * 64; i += 256) W1l[i] = W1[i];
    for (int i = tid; i < 64 * 32; i += 256) W2l[i] = W2[i];
    __syncthreads();

    const int slot = tid >> 4;
    const int lane = tid & 15;
    float bj0 = b1[lane * 4 + 0], bj1 = b1[lane * 4 + 1];
    float bj2 = b1[lane * 4 + 2], bj3 = b1[lane * 4 + 3];

    const int ngroups = (n + 15) >> 4;
    for (int g = blockIdx.x; g < ngroups; g += gridDim.x) {
        const int node = g * 16 + slot;
        if (node >= n) continue;

        float4 a0 = {0, 0, 0, 0}, a1 = {0, 0, 0, 0}, a2 = {0, 0, 0, 0}, a3 = {0, 0, 0, 0};
        const int beg = row_ptr[node], end = row_ptr[node + 1];
        int i = beg;
        for (; i + 4 <= end; i += 4) {
            int s0 = csr_src[i], s1 = csr_src[i + 1], s2 = csr_src[i + 2], s3 = csr_src[i + 3];
            float4 v0 = x4[(size_t)s0 * 16 + lane];
            float4 v1 = x4[(size_t)s1 * 16 + lane];
            float4 v2 = x4[(size_t)s2 * 16 + lane];
            float4 v3 = x4[(size_t)s3 * 16 + lane];
            float w0 = ns[s0], w1 = ns[s1], w2 = ns[s2], w3 = ns[s3];
            a0.x = fmaf(v0.x, w0, a0.x); a0.y = fmaf(v0.y, w0, a0.y);
            a0.z = fmaf(v0.z, w0, a0.z); a0.w = fmaf(v0.w, w0, a0.w);
            a1.x = fmaf(v1.x, w1, a1.x); a1.y = fmaf(v1.y, w1, a1.y);
            a1.z = fmaf(v1.z, w1, a1.z); a1.w = fmaf(v1.w, w1, a1.w);
            a2.x = fmaf(v2.x, w2, a2.x); a2.y = fmaf(v2.y, w2, a2.y);
            a2.z = fmaf(v2.z, w2, a2.z); a2.w = fmaf(v2.w, w2, a2.w);
            a3.x = fmaf(v3.x, w3, a3.x); a3.y = fmaf(v3.y, w3, a3.y);
            a3.z = fmaf(v3.z, w3, a3.z); a3.w = fmaf(v3.w, w3, a3.w);
        }
        for (; i < end; ++i) {
            int s = csr_src[i];
            float4 v = x4[(size_t)s * 16 + lane];
            float w = ns[s];
            a0.x = fmaf(v.x, w, a0.x); a0.y = fmaf(v.y, w, a0.y);
            a0.z = fmaf(v.z, w, a0.z); a0.w = fmaf(v.w, w, a0.w);
        }
        const float ndv = nd[node];
        float rx = (a0.x + a1.x + a2.x + a3.x) * ndv;
        float ry = (a0.y + a1.y + a2.y + a3.y) * ndv;
        float rz = (a0.z + a1.z + a2.z + a3.z) * ndv;
        float rw = (a0.w + a1.w + a2.w + a3.w) * ndv;

        WAVE_BAR();  // prior iteration's GEMM2 reads done before overwrite
        rows[slot][lane * 4 + 0] = rx;
        rows[slot][lane * 4 + 1] = ry;
        rows[slot][lane * 4 + 2] = rz;
        rows[slot][lane * 4 + 3] = rw;
        WAVE_BAR();  // agg row visible to all 16 lanes of this slot

        float o0 = bj0, o1 = bj1, o2 = bj2, o3 = bj3;
#pragma unroll
        for (int k = 0; k < 64; ++k) {
            const float r = rows[slot][k];
            o0 = fmaf(r, W1l[k * 64 + lane * 4 + 0], o0);
            o1 = fmaf(r, W1l[k * 64 + lane * 4 + 1], o1);
            o2 = fmaf(r, W1l[k * 64 + lane * 4 + 2], o2);
            o3 = fmaf(r, W1l[k * 64 + lane * 4 + 3], o3);
        }
        const float nsv = ns[node];
        o0 = fmaxf(o0, 0.0f) * nsv; o1 = fmaxf(o1, 0.0f) * nsv;
        o2 = fmaxf(o2, 0.0f) * nsv; o3 = fmaxf(o3, 0.0f) * nsv;

        WAVE_BAR();  // GEMM1 reads done before h1s overwrite
        rows[slot][lane * 4 + 0] = o0;
        rows[slot][lane * 4 + 1] = o1;
        rows[slot][lane * 4 + 2] = o2;
        rows[slot][lane * 4 + 3] = o3;
        WAVE_BAR();  // h1s row visible

        float p0 = 0.0f, p1 = 0.0f;
#pragma unroll
        for (int k = 0; k < 64; ++k) {
            const float r = rows[slot][k];
            p0 = fmaf(r, W2l[k * 32 + lane * 2 + 0], p0);
            p1 = fmaf(r, W2l[k * 32 + lane * 2 + 1], p1);
        }
        t2[(size_t)node * 32 + lane * 2 + 0] = p0;
        t2[(size_t)node * 32 + lane * 2 + 1] = p1;
    }
}

// ---------------------------------------------------------------------------
// Layer 2: out[v] = relu(nd[v] * sum_{s in in(v)} t2[s] + b2)
// 8 lanes x float4 per node, 32 nodes per 256-thr block, 4-way unroll.
// ---------------------------------------------------------------------------
__global__ __launch_bounds__(256) void layer2_kernel(
    const float4* __restrict__ t24, const float* __restrict__ nd,
    const int* __restrict__ row_ptr, const int* __restrict__ csr_src,
    const float* __restrict__ b2, float4* __restrict__ out4, int n) {
    const int t = blockIdx.x * blockDim.x + threadIdx.x;
    const int node = t >> 3;
    const int lane = t & 7;
    if (node >= n) return;

    float4 a0 = {0, 0, 0, 0}, a1 = {0, 0, 0, 0}, a2 = {0, 0, 0, 0}, a3 = {0, 0, 0, 0};
    const int beg = row_ptr[node], end = row_ptr[node + 1];
    int i = beg;
    for (; i + 4 <= end; i += 4) {
        int s0 = csr_src[i], s1 = csr_src[i + 1], s2 = csr_src[i + 2], s3 = csr_src[i + 3];
        float4 v0 = t24[(size_t)s0 * 8 + lane];
        float4 v1 = t24[(size_t)s1 * 8 + lane];
        float4 v2 = t24[(size_t)s2 * 8 + lane];
        float4 v3 = t24[(size_t)s3 * 8 + lane];
        a0.x += v0.x; a0.y += v0.y; a0.z += v0.z; a0.w += v0.w;
        a1.x += v1.x; a1.y += v1.y; a1.z += v1.z; a1.w += v1.w;
        a2.x += v2.x; a2.y += v2.y; a2.z += v2.z; a2.w += v2.w;
        a3.x += v3.x; a3.y += v3.y; a3.z += v3.z; a3.w += v3.w;
    }
    for (; i < end; ++i) {
        float4 v = t24[(size_t)csr_src[i] * 8 + lane];
        a0.x += v.x; a0.y += v.y; a0.z += v.z; a0.w += v.w;
    }
    const float ndv = nd[node];
    const float4 bb = ((const float4*)b2)[lane];
    float4 r;
    r.x = fmaxf(fmaf(a0.x + a1.x + a2.x + a3.x, ndv, bb.x), 0.0f);
    r.y = fmaxf(fmaf(a0.y + a1.y + a2.y + a3.y, ndv, bb.y), 0.0f);
    r.z = fmaxf(fmaf(a0.z + a1.z + a2.z + a3.z, ndv, bb.z), 0.0f);
    r.w = fmaxf(fmaf(a0.w + a1.w + a2.w + a3.w, ndv, bb.w), 0.0f);
    out4[(size_t)node * 8 + lane] = r;
}

extern "C" void kernel_launch(void* const* d_in, const int* in_sizes, int n_in,
                              void* d_out, int out_size, void* d_ws, size_t ws_size,
                              hipStream_t stream) {
    const float* x  = (const float*)d_in[0];
    const int* ei   = (const int*)d_in[1];
    const float* W1 = (const float*)d_in[2];
    const float* b1 = (const float*)d_in[3];
    const float* W2 = (const float*)d_in[4];
    const float* b2 = (const float*)d_in[5];
    float* out = (float*)d_out;

    const int n  = in_sizes[0] / IN_F;  // 100000
    const int nE = in_sizes[1] / 2;     // 1000000
    const int* src = ei;
    const int* dst = ei + nE;

    // workspace: din[n] dout[n] row_ptr[n+4] bsums[512] rank[nE] csr_src[nE]
    //            ns[n] nd[n] t2[n*32]   (~25 MB, all 16B-aligned)
    int* din     = (int*)d_ws;
    int* dout    = din + n;
    int* row_ptr = dout + n;
    int* bsums   = row_ptr + n + 4;
    int* rank    = bsums + 512;
    int* csr_src = rank + nE;
    float* ns    = (float*)(csr_src + nE);
    float* nd    = ns + n;
    float* t2    = nd + n;

    // zero only din+dout (contiguous prefix)
    hipMemsetAsync(d_ws, 0, (size_t)2 * n * sizeof(int), stream);

    const int e8b = (nE / 8 + 255) / 256 + 1;  // 8 edges/thread (tail-guarded)
    const int nb = (n + SCAN_B - 1) / SCAN_B;  // 391 <= 512

    degree_rank_kernel<<<e8b, 256, 0, stream>>>(src, dst, dout, din, rank, nE);
    scan_norm_block<<<nb, SCAN_B, 0, stream>>>(din, dout, ns, nd, row_ptr, bsums, n);
    scan_sums<<<1, 512, 0, stream>>>(bsums, nb);
    scan_add<<<nb, SCAN_B, 0, stream>>>(row_ptr, bsums, n, nE);
    fill_csr<<<e8b, 256, 0, stream>>>(src, dst, rank, row_ptr, csr_src, nE);

    layer1_kernel<<<2048, 256, 0, stream>>>(
        (const float4*)x, ns, nd, row_ptr, csr_src, W1, b1, W2, t2, n);
    layer2_kernel<<<(n * 8 + 255) / 256, 256, 0, stream>>>(
        (const float4*)t2, nd, row_ptr, csr_src, b2, (float4*)out, n);
}